// Round 5
// baseline (302.206 us; speedup 1.0000x reference)
//
#include <hip/hip_runtime.h>
#include <math.h>

#define kB 2
#define kS 2048
#define kD 1024
#define kH 16
#define kM (kB * kS)     /* 4096 */

typedef unsigned short u16;
typedef unsigned int u32;
typedef unsigned long long u64;
typedef short s16x8 __attribute__((ext_vector_type(8)));     /* bf16 MFMA frag */
typedef float f32x4 __attribute__((ext_vector_type(4)));     /* MFMA acc */
typedef u16 u16x8 __attribute__((ext_vector_type(8)));

/* fp32 -> bf16 round-to-nearest-even (scalar) */
__device__ __forceinline__ u16 f2bf(float f) {
    u32 u = __float_as_uint(f);
    u += 0x7FFFu + ((u >> 16) & 1u);
    return (u16)(u >> 16);
}

/* pack two fp32 -> two bf16 in one u32 (round-half-up + v_perm) */
__device__ __forceinline__ u32 pack_bf2(float f0, float f1) {
    const u32 r0 = __float_as_uint(f0) + 0x8000u;
    const u32 r1 = __float_as_uint(f1) + 0x8000u;
    return __builtin_amdgcn_perm(r1, r0, 0x07060302u);  /* [bf16(f1):bf16(f0)] */
}

typedef __attribute__((address_space(1))) void as1_void;
typedef __attribute__((address_space(3))) void as3_void;
__device__ __forceinline__ void async_copy16(const void* g, void* l) {
    __builtin_amdgcn_global_load_lds((as1_void*)(unsigned long long)g,
                                     (as3_void*)(unsigned)(unsigned long long)l,
                                     16, 0, 0);
}

/* ---------------- fused prep: bf16 converts + dense u16 AND-mask ----------------
 * blocks [0,12288): X converts (3 x 4096)
 * blocks [12288,16384): W converts (4 x 1024)
 * blocks [16384,20480): mask expand: Msx[b*kS+q][k] = mask ? 0xFFFF : 0
 *   (fully coalesced: thread reads 8 ints (2x int4), writes 16B of u16)
 */
__global__ __launch_bounds__(256) void prep(
        const float* __restrict__ xq, const float* __restrict__ xk, const float* __restrict__ xv,
        const float* __restrict__ Wq, const float* __restrict__ Wk,
        const float* __restrict__ Wv, const float* __restrict__ Wo,
        const int* __restrict__ msk,
        u16* __restrict__ xqb, u16* __restrict__ xkb, u16* __restrict__ xvb,
        u16* __restrict__ wqb, u16* __restrict__ wkb, u16* __restrict__ wvb,
        u16* __restrict__ wob, u16* __restrict__ Msx) {
    const int bid = blockIdx.x;
    const int tid = threadIdx.x;
    if (bid < 16384) {
        const float* in;
        u16* out;
        int i;
        if (bid < 12288) {
            const int z = bid >> 12;
            in = z == 0 ? xq : (z == 1 ? xk : xv);
            out = z == 0 ? xqb : (z == 1 ? xkb : xvb);
            i = (bid & 4095) * 256 + tid;
        } else {
            const int z = (bid - 12288) >> 10;
            in = z == 0 ? Wq : (z == 1 ? Wk : (z == 2 ? Wv : Wo));
            out = z == 0 ? wqb : (z == 1 ? wkb : (z == 2 ? wvb : wob));
            i = ((bid - 12288) & 1023) * 256 + tid;
        }
        const float4 v = ((const float4*)in)[i];
        ushort4 o;
        o.x = f2bf(v.x); o.y = f2bf(v.y); o.z = f2bf(v.z); o.w = f2bf(v.w);
        ((ushort4*)out)[i] = o;
    } else {
        const int mid = (bid - 16384) * 256 + tid;          /* 0..1048575 */
        const int c = mid & 255;                            /* 8-key chunk */
        const int row = mid >> 8;                           /* b*kS + q    */
        const int4* src = (const int4*)(msk + (size_t)row * kS + c * 8);
        const int4 v0 = src[0];
        const int4 v1 = src[1];
        u16x8 o;
        o[0] = v0.x ? 0xFFFFu : 0; o[1] = v0.y ? 0xFFFFu : 0;
        o[2] = v0.z ? 0xFFFFu : 0; o[3] = v0.w ? 0xFFFFu : 0;
        o[4] = v1.x ? 0xFFFFu : 0; o[5] = v1.y ? 0xFFFFu : 0;
        o[6] = v1.z ? 0xFFFFu : 0; o[7] = v1.w ? 0xFFFFu : 0;
        *(u16x8*)(Msx + (size_t)row * kS + c * 8) = o;
    }
}

/* ---------------- bf16 GEMM: C = A[M,K] @ W[N,K]^T + bias ----------------
 * 128x128 tile, BK=32, 4 waves (2x2 of 64x64), 16x16x32 MFMA,
 * global_load_lds width-16, XOR-swizzled LDS (chunk c of row r at slot c^(r&3)).
 * MODE 0: bf16 out; MODE 2: f32 out; MODE 3: V^T out [(b*H+h)*64+d][s].
 */
template <int MODE>
__device__ __forceinline__ void gemm_bt_body(const u16* __restrict__ A,
                                             const u16* __restrict__ W,
                                             const float* __restrict__ bias,
                                             void* __restrict__ Cp) {
    __shared__ u16 As[128 * 32];
    __shared__ u16 Bs[128 * 32];
    const int tid = threadIdx.x;
    const int wave = tid >> 6, lane = tid & 63;
    const int l15 = lane & 15, quad = lane >> 4;
    const int wr = wave >> 1, wc = wave & 1;
    const int m0 = (MODE == 3 ? blockIdx.x : blockIdx.y) * 128;
    const int n0 = (MODE == 3 ? blockIdx.y : blockIdx.x) * 128;

    const int srow = lane >> 2;                       /* 0..15 */
    const int schk = (lane & 3) ^ (srow & 3);
    const u16* gA0 = A + (size_t)(m0 + 32 * wave + srow) * kD + schk * 8;
    const u16* gA1 = gA0 + 16 * kD;
    const u16* gB0 = W + (size_t)(n0 + 32 * wave + srow) * kD + schk * 8;
    const u16* gB1 = gB0 + 16 * kD;
    u16* lA0 = As + (32 * wave) * 32;
    u16* lA1 = lA0 + 16 * 32;
    u16* lB0 = Bs + (32 * wave) * 32;
    u16* lB1 = lB0 + 16 * 32;

    const int rdoff = (quad ^ (l15 & 3)) * 8;

    f32x4 acc[4][4];
#pragma unroll
    for (int i = 0; i < 4; ++i)
#pragma unroll
        for (int j = 0; j < 4; ++j) acc[i][j] = (f32x4)0.f;

    for (int kt = 0; kt < kD; kt += 32) {
        __syncthreads();
        async_copy16(gA0 + kt, lA0);
        async_copy16(gA1 + kt, lA1);
        async_copy16(gB0 + kt, lB0);
        async_copy16(gB1 + kt, lB1);
        __syncthreads();

        s16x8 af[4], bf[4];
#pragma unroll
        for (int fm = 0; fm < 4; ++fm)
            af[fm] = *(const s16x8*)(As + (wr * 64 + fm * 16 + l15) * 32 + rdoff);
#pragma unroll
        for (int fn = 0; fn < 4; ++fn)
            bf[fn] = *(const s16x8*)(Bs + (wc * 64 + fn * 16 + l15) * 32 + rdoff);
#pragma unroll
        for (int fm = 0; fm < 4; ++fm)
#pragma unroll
            for (int fn = 0; fn < 4; ++fn)
                acc[fm][fn] = __builtin_amdgcn_mfma_f32_16x16x32_bf16(
                    af[fm], bf[fn], acc[fm][fn], 0, 0, 0);
    }

    if constexpr (MODE == 3) {
#pragma unroll
        for (int fn = 0; fn < 4; ++fn) {
            const int sglob = n0 + wc * 64 + fn * 16 + l15;
            const int bb = sglob >> 11, ss = sglob & (kS - 1);
#pragma unroll
            for (int fm = 0; fm < 4; ++fm) {
                const int dglob = m0 + wr * 64 + fm * 16 + quad * 4;
                const float4 b4 = *(const float4*)(bias + dglob);
                const float bb4[4] = {b4.x, b4.y, b4.z, b4.w};
                const int hh = dglob >> 6, dd = dglob & 63;
                u16* base = (u16*)Cp + ((size_t)(bb * kH + hh) * 64 + dd) * kS + ss;
#pragma unroll
                for (int r = 0; r < 4; ++r)
                    base[(size_t)r * kS] = f2bf(acc[fm][fn][r] + bb4[r]);
            }
        }
    } else {
#pragma unroll
        for (int fn = 0; fn < 4; ++fn) {
            const int col = n0 + wc * 64 + fn * 16 + l15;
            const float bv = bias[col];
#pragma unroll
            for (int fm = 0; fm < 4; ++fm) {
                const int row = m0 + wr * 64 + fm * 16 + quad * 4;
#pragma unroll
                for (int r = 0; r < 4; ++r) {
                    const float v = acc[fm][fn][r] + bv;
                    if constexpr (MODE == 0)
                        ((u16*)Cp)[(size_t)(row + r) * kD + col] = f2bf(v);
                    else
                        ((float*)Cp)[(size_t)(row + r) * kD + col] = v;
                }
            }
        }
    }
}

__global__ __launch_bounds__(256) void qkv_gemm(
        const u16* __restrict__ xq, const u16* __restrict__ xk, const u16* __restrict__ xv,
        const u16* __restrict__ wq, const u16* __restrict__ wk, const u16* __restrict__ wv,
        const float* __restrict__ bq, const float* __restrict__ bk, const float* __restrict__ bv,
        u16* __restrict__ q, u16* __restrict__ k, u16* __restrict__ vt) {
    const int z = blockIdx.z;
    if (z == 0)      gemm_bt_body<0>(xq, wq, bq, q);
    else if (z == 1) gemm_bt_body<0>(xk, wk, bk, k);
    else             gemm_bt_body<3>(wv, xv, bv, vt);   /* V^T = Wv · X^T */
}

__global__ __launch_bounds__(256) void o_gemm(const u16* __restrict__ A,
                                              const u16* __restrict__ W,
                                              const float* __restrict__ bias,
                                              float* __restrict__ C) {
    gemm_bt_body<2>(A, W, bias, C);
}

/* ---------------- MFMA flash attention v3 ----------------
 * Block = (128-query tile, b*h); 4 waves, wave w owns queries [32w,32w+32).
 * K/V fragments reused across 2 query groups (halved LDS bytes/MAC).
 * Scores^T = K·Q^T (D[key][query]); fixed-max softmax p=exp2(fma(s,kC,-8)).
 * Mask: dense u16 AND applied to packed bf16 P pairs (address shared with
 * P write). Row-sum l via ones-MFMA accumulated in fp32 across all tiles.
 * QPs: Q staged, frags hoisted, then buffer reused for P (wave-private rows).
 */
#define kC 0.180336880f   /* 0.125 * log2(e) */

__global__ __launch_bounds__(256) void attn_mfma(const u16* __restrict__ Qb,
                                                 const u16* __restrict__ Kb,
                                                 const u16* __restrict__ Vt,
                                                 const u16* __restrict__ Msx,
                                                 u16* __restrict__ Ob) {
    __shared__ u16 QPs[128 * 64];   /* Q then P */
    __shared__ u16 Ks[64 * 64];
    __shared__ u16 Vs[64 * 64];
    __shared__ u16 Ms[128 * 64];

    const int tid = threadIdx.x;
    const int wave = tid >> 6, lane = tid & 63;
    const int l15 = lane & 15, quad = lane >> 4, l7 = lane & 7;
    const int q0 = blockIdx.x * 128;
    const int b = blockIdx.y >> 4, h = blockIdx.y & 15;

    const int srow = lane >> 3;           /* 0..7 */
    const int schk = l7 ^ srow;

    /* stage Q once: wave covers rows [32w, 32w+32) */
    const u16* gQ = Qb + ((size_t)(b * kS + q0 + 32 * wave + srow)) * kD + h * 64 + schk * 8;
#pragma unroll
    for (int i = 0; i < 4; ++i)
        async_copy16(gQ + (size_t)(8 * i) * kD, QPs + (32 * wave + 8 * i) * 64);

    const u16* gK = Kb + ((size_t)(b * kS + 16 * wave + srow)) * kD + h * 64 + schk * 8;
    const u16* gV = Vt + ((size_t)((b * kH + h) * 64 + 16 * wave + srow)) * kS + schk * 8;
    const u16* gM = Msx + ((size_t)(b * kS + q0 + 32 * wave + srow)) * kS + schk * 8;

    f32x4 oacc[2][4];
#pragma unroll
    for (int g = 0; g < 2; ++g)
#pragma unroll
        for (int i = 0; i < 4; ++i) oacc[g][i] = (f32x4)0.f;
    f32x4 lacc[2];
    lacc[0] = (f32x4)0.f; lacc[1] = (f32x4)0.f;

    s16x8 ones;
#pragma unroll
    for (int j = 0; j < 8; ++j) ones[j] = (short)0x3F80;   /* bf16 1.0 */

    __syncthreads();   /* Q landed */
    s16x8 qf[2][2];
#pragma unroll
    for (int qg = 0; qg < 2; ++qg)
#pragma unroll
        for (int kc = 0; kc < 2; ++kc)
            qf[qg][kc] = *(const s16x8*)(QPs + (32 * wave + qg * 16 + l15) * 64 +
                                         ((kc * 4 + quad) ^ l7) * 8);

    for (int kt = 0; kt < kS; kt += 64) {
        __syncthreads();                  /* prev K/V/P reads done (Q frags at kt=0) */
        async_copy16(gK + (size_t)kt * kD, Ks + (16 * wave) * 64);
        async_copy16(gK + (size_t)(kt + 8) * kD, Ks + (16 * wave + 8) * 64);
        async_copy16(gV + kt, Vs + (16 * wave) * 64);
        async_copy16(gV + 8 * kS + kt, Vs + (16 * wave + 8) * 64);
#pragma unroll
        for (int i = 0; i < 4; ++i)
            async_copy16(gM + (size_t)(8 * i) * kS + kt, Ms + (32 * wave + 8 * i) * 64);
        __syncthreads();                  /* staging landed */

        /* scores^T: D[key][query]; K frags shared by both query groups */
        f32x4 s[2][4];
#pragma unroll
        for (int qg = 0; qg < 2; ++qg)
#pragma unroll
            for (int fn = 0; fn < 4; ++fn) s[qg][fn] = (f32x4)0.f;
#pragma unroll
        for (int kc = 0; kc < 2; ++kc)
#pragma unroll
            for (int fn = 0; fn < 4; ++fn) {
                const s16x8 ak = *(const s16x8*)(Ks + (fn * 16 + l15) * 64 +
                                                 ((kc * 4 + quad) ^ l7) * 8);
#pragma unroll
                for (int qg = 0; qg < 2; ++qg)
                    s[qg][fn] = __builtin_amdgcn_mfma_f32_16x16x32_bf16(
                        ak, qf[qg][kc], s[qg][fn], 0, 0, 0);
            }

        /* softmax (fixed-max) + pack + mask-AND + write P */
#pragma unroll
        for (int qg = 0; qg < 2; ++qg) {
            const int base = (32 * wave + qg * 16 + l15) * 64;
#pragma unroll
            for (int fn = 0; fn < 4; ++fn) {
                const float p0 = exp2f(fmaf(s[qg][fn][0], kC, -8.0f));
                const float p1 = exp2f(fmaf(s[qg][fn][1], kC, -8.0f));
                const float p2 = exp2f(fmaf(s[qg][fn][2], kC, -8.0f));
                const float p3 = exp2f(fmaf(s[qg][fn][3], kC, -8.0f));
                const int off = base + ((fn * 2 + (quad >> 1)) ^ l7) * 8 + (quad & 1) * 4;
                const uint2 m2 = *(const uint2*)(Ms + off);
                uint2 o;
                o.x = pack_bf2(p0, p1) & m2.x;
                o.y = pack_bf2(p2, p3) & m2.y;
                *(uint2*)(QPs + off) = o;
            }
        }

        /* PV + l: V frags shared by both query groups; l via ones-MFMA */
#pragma unroll
        for (int kc = 0; kc < 2; ++kc) {
            s16x8 av[4];
#pragma unroll
            for (int fd = 0; fd < 4; ++fd)
                av[fd] = *(const s16x8*)(Vs + (fd * 16 + l15) * 64 +
                                         ((kc * 4 + quad) ^ l7) * 8);
#pragma unroll
            for (int qg = 0; qg < 2; ++qg) {
                const s16x8 bp = *(const s16x8*)(QPs + (32 * wave + qg * 16 + l15) * 64 +
                                                 ((kc * 4 + quad) ^ l7) * 8);
                lacc[qg] = __builtin_amdgcn_mfma_f32_16x16x32_bf16(ones, bp, lacc[qg], 0, 0, 0);
#pragma unroll
                for (int fd = 0; fd < 4; ++fd)
                    oacc[qg][fd] = __builtin_amdgcn_mfma_f32_16x16x32_bf16(
                        av[fd], bp, oacc[qg][fd], 0, 0, 0);
            }
        }
    }

    /* epilogue: O^T[d][q] -> Ob[q][h*64+d] */
#pragma unroll
    for (int qg = 0; qg < 2; ++qg) {
        const float inv = 1.f / lacc[qg][0];
        const size_t orow = (size_t)(b * kS + q0 + 32 * wave + qg * 16 + l15);
#pragma unroll
        for (int fd = 0; fd < 4; ++fd) {
            uint2 o;
            o.x = pack_bf2(oacc[qg][fd][0] * inv, oacc[qg][fd][1] * inv);
            o.y = pack_bf2(oacc[qg][fd][2] * inv, oacc[qg][fd][3] * inv);
            *(uint2*)(Ob + orow * kD + h * 64 + fd * 16 + quad * 4) = o;
        }
    }
}

extern "C" void kernel_launch(void* const* d_in, const int* in_sizes, int n_in,
                              void* d_out, int out_size, void* d_ws, size_t ws_size,
                              hipStream_t stream) {
    const float* xq = (const float*)d_in[0];
    const float* xk = (const float*)d_in[1];
    const float* xv = (const float*)d_in[2];
    const int*  msk = (const int*)d_in[3];
    const float* Wq = (const float*)d_in[4];
    const float* bq = (const float*)d_in[5];
    const float* Wk = (const float*)d_in[6];
    const float* bk = (const float*)d_in[7];
    const float* Wv = (const float*)d_in[8];
    const float* bv = (const float*)d_in[9];
    const float* Wo = (const float*)d_in[10];
    const float* bo = (const float*)d_in[11];
    float* out = (float*)d_out;

    const size_t NX = (size_t)kM * kD;      /* 4,194,304 */
    const size_t NW = (size_t)kD * kD;      /* 1,048,576 */
    const size_t NM = (size_t)kB * kS * kS; /* 8,388,608 */

    u16* p = (u16*)d_ws;
    u16* Msx = p; p += NM;                  /* 16 MiB */
    u16* xqb = p; p += NX;
    u16* xkb = p; p += NX;
    u16* xvb = p; p += NX;
    u16* wqb = p; p += NW;
    u16* wkb = p; p += NW;
    u16* wvb = p; p += NW;
    u16* wob = p; p += NW;
    u16* qb  = p; p += NX;
    u16* kb  = p; p += NX;
    u16* vtb = p; p += NX;
    u16* ab  = xqb;                         /* reuse: xqb dead after qkv_gemm */

    prep<<<20480, 256, 0, stream>>>(xq, xk, xv, Wq, Wk, Wv, Wo, msk,
                                    xqb, xkb, xvb, wqb, wkb, wvb, wob, Msx);

    dim3 gq(kD / 128, kM / 128, 3);
    qkv_gemm<<<gq, 256, 0, stream>>>(xqb, xkb, xvb, wqb, wkb, wvb, bq, bk, bv, qb, kb, vtb);

    dim3 ga(kS / 128, kB * kH);             /* (16,32) = 512 blocks */
    attn_mfma<<<ga, 256, 0, stream>>>(qb, kb, vtb, Msx, ab);

    dim3 go(kD / 128, kM / 128);
    o_gemm<<<go, 256, 0, stream>>>(ab, wob, bo, out);
}